// Round 15
// baseline (7558.611 us; speedup 1.0000x reference)
//
#include <hip/hip_runtime.h>
#include <hip/hip_bf16.h>

// NeuralODE Bosh3 — Round 15: 8-way model-parallel, LDS-resident weights,
// sc0/sc1 L3 exchange (r14), plus TWO-TILE PING-PONG: each block serves two
// independent 32-row batch groups (gA, gB=gA+32) with separate buffers and
// counters. Phase order waitA-Pa-sigA / waitB-Pb-sigB hides each tile's
// sync round-trip + skew behind the other tile's compute. Same weights LDS
// slice serves both tiles. r14 was sync-latency bound: 6us/phase exposed.

#define B_ 2048
#define L_ 128
#define P_ 8
#define T_ 128
#define GT_ 32                 // batch rows per group
#define NGRP (B_/GT_)          // 64 groups
#define NBLK 256

typedef __attribute__((ext_vector_type(8))) short short8;
typedef __attribute__((ext_vector_type(4))) float f32x4;
typedef __attribute__((ext_vector_type(4))) unsigned int u32x4;

// wp layout (ushort units). 800 frags x 512, member-major (as r13/r14):
//   member m slice at m*51200; within: r<20: W0 (ntl=r/5,kt=r%5);
//   r in [20,84): W1 (q=r-20, ntl=q>>4, kt=q&15); r in [84,100): W2 (kt=r-84)
#define WTOT (800*512)
#define CNT_OFF (WTOT + 256)        // 64 x u32 counters (128 ushorts)
#define EXB (WTOT + 256 + 128)
#define XSTR 160                    // x row stride (ushorts)
#define GSTR (GT_*XSTR + 2*GT_*512) // per-group: x + h1 + h2 = 37888 ushorts

#define VMW0 asm volatile("s_waitcnt vmcnt(0)" ::: "memory")
#define SCHB __builtin_amdgcn_sched_barrier(0)

__device__ __forceinline__ unsigned short f2bf(float f){
  unsigned u = __builtin_bit_cast(unsigned, f);
  u += 0x7fffu + ((u >> 16) & 1u);
  return (unsigned short)(u >> 16);
}

__device__ __forceinline__ float tanh_fast(float x){
  float e = __expf(2.0f * x);
  return 1.0f - __fdividef(2.0f, e + 1.0f);
}

// device-coherent (L3-point) 16B load / 2B store
__device__ __forceinline__ short8 ld_dev(const unsigned short* p){
  u32x4 r;
  asm volatile("global_load_dwordx4 %0, %1, off sc0 sc1"
               : "=v"(r) : "v"(p) : "memory");
  return __builtin_bit_cast(short8, r);
}
__device__ __forceinline__ void st_dev16(unsigned short* p, unsigned short v){
  unsigned vv = v;
  asm volatile("global_store_short %0, %1, off sc0 sc1"
               :: "v"(p), "v"(vv) : "memory");
}

__global__ void prep_weights(const float* __restrict__ W0,
                             const float* __restrict__ W1,
                             const float* __restrict__ W2,
                             const float* __restrict__ ts,
                             unsigned short* __restrict__ wp){
  int idx = blockIdx.x * blockDim.x + threadIdx.x;
  if (idx >= WTOT){
    int t = idx - WTOT;
    if (t < T_ - 1){
      float* dts = (float*)(wp + WTOT);
      dts[t] = ts[t+1] - ts[t];
    } else if (t >= 128 && t < 192){
      ((unsigned*)(wp + CNT_OFF))[t - 128] = 0u;   // 64 counters, each launch
    }
    return;
  }
  int e = idx & 511, f = idx >> 9;
  int j = e & 7, lane = e >> 3;
  int m = f / 100, r = f % 100;
  const float* src; int nt, kt, Korig;
  if (r < 20)      { src = W0; Korig = 136; nt = 4*m + r/5;        kt = r%5; }
  else if (r < 84) { int q = r-20; src = W1; Korig = 512; nt = 4*m + (q>>4); kt = q&15; }
  else             { src = W2; Korig = 512; nt = m;                kt = r-84; }
  int row = nt*16 + (lane & 15);
  int k   = kt*32 + ((lane >> 4) << 3) + j;
  float v = (k < Korig) ? src[row*Korig + k] : 0.0f;
  wp[idx] = f2bf(v);
}

__global__ __launch_bounds__(256, 1)
void ode_main(const float* __restrict__ x0,
              const float* __restrict__ args,
              const float* __restrict__ b0, const float* __restrict__ b1,
              const float* __restrict__ b2,
              unsigned short* wp,
              float* __restrict__ out){
  __shared__ __align__(16) unsigned short wlds[100*512];   // 100 KiB weights
  __shared__ float dtl[T_];

  const int tid  = threadIdx.x;
  const int lane = tid & 63;
  const int wv   = tid >> 6;        // wave 0..3
  const int lo   = lane & 15;
  const int hi   = lane >> 4;
  const int qn   = wv >> 1;         // nt-pair: nts {2qn, 2qn+1}
  const int pan  = wv & 1;          // row panel 0/1 (16 rows each)
  const int bid  = blockIdx.x;
  const int m    = (bid >> 3) & 7;              // member (model slice)
  const int gA   = (bid & 7)*4 + (bid >> 6);    // group A (XCD-local-ish)
  const int gB   = gA + 32;                     // group B
  const int r0A  = gA * GT_;
  const int r0B  = gB * GT_;

  unsigned* cA = (unsigned*)(wp + CNT_OFF) + gA;
  unsigned* cB = (unsigned*)(wp + CNT_OFF) + gB;
  unsigned short* gxA = wp + EXB + (size_t)gA * GSTR;
  unsigned short* h1A = gxA + GT_*XSTR;
  unsigned short* h2A = h1A + GT_*512;
  unsigned short* gxB = wp + EXB + (size_t)gB * GSTR;
  unsigned short* h1B = gxB + GT_*XSTR;
  unsigned short* h2B = h1B + GT_*512;

  // weights slice -> LDS (once)
  {
    const u32x4* s = (const u32x4*)(wp + (size_t)m * 51200);
    u32x4* d = (u32x4*)wlds;
    for (int i = tid; i < 6400; i += 256) d[i] = s[i];
  }
  if (tid < T_-1) dtl[tid] = ((const float*)(wp + WTOT))[tid];

  float b0v[2], b1v[2];
  #pragma unroll
  for (int n = 0; n < 2; ++n){
    b0v[n] = b0[(4*m + 2*qn + n)*16 + lo];
    b1v[n] = b1[(4*m + 2*qn + n)*16 + lo];
  }
  const int c3 = m*16 + lo;
  const float b2v = b2[c3];
  const bool st_own = (wv < 2);     // waves 0,1 own state (panel = wv)

  float yrA[4], ynA[4], yrB[4], ynB[4];
  if (st_own){
    #pragma unroll
    for (int j = 0; j < 4; ++j){
      int row = pan*16 + 4*hi + j;
      float vA = x0[(r0A + row)*L_ + c3];
      float vB = x0[(r0B + row)*L_ + c3];
      yrA[j] = vA; yrB[j] = vB;
      __builtin_nontemporal_store(vA, &out[((r0A + row)*T_ + 0)*L_ + c3]);
      __builtin_nontemporal_store(vB, &out[((r0B + row)*T_ + 0)*L_ + c3]);
      st_dev16(gxA + row*XSTR + c3, f2bf(vA));
      st_dev16(gxB + row*XSTR + c3, f2bf(vB));
    }
  }
  if (m == 0){   // args + zero pad cols 128..159, both tiles
    for (int i = tid; i < GT_*32; i += 256){
      int row = i >> 5, cc = 128 + (i & 31);
      unsigned short vA = (cc < 136) ? f2bf(args[(r0A + row)*P_ + (cc-128)]) : (unsigned short)0;
      unsigned short vB = (cc < 136) ? f2bf(args[(r0B + row)*P_ + (cc-128)]) : (unsigned short)0;
      st_dev16(gxA + row*XSTR + cc, vA);
      st_dev16(gxB + row*XSTR + cc, vB);
    }
  }

  unsigned tgtA = 8, tgtB = 8;
  auto sig = [&](unsigned* c){
    VMW0;                     // my sc1 stores reached L3
    __syncthreads();          // all waves flushed
    if (tid == 0)
      __hip_atomic_fetch_add(c, 1u, __ATOMIC_RELAXED, __HIP_MEMORY_SCOPE_AGENT);
  };
  auto wait = [&](unsigned* c, unsigned& tgt){
    if (tid == 0){
      while (__hip_atomic_load(c, __ATOMIC_RELAXED, __HIP_MEMORY_SCOPE_AGENT) < tgt)
        __builtin_amdgcn_s_sleep(1);
    }
    __syncthreads();
    tgt += 8;
  };

  sig(cA); sig(cB);   // init exchange published

  // ---- phases (per tile) ----
  auto phase1 = [&](unsigned short* gx, unsigned short* h1T){
    short8 xa[5];
    #pragma unroll
    for (int kt = 0; kt < 5; ++kt)
      xa[kt] = ld_dev(gx + (pan*16 + lo)*XSTR + kt*32 + (hi<<3));
    VMW0; SCHB;
    f32x4 acc[2]; acc[0] = f32x4{0,0,0,0}; acc[1] = f32x4{0,0,0,0};
    #pragma unroll
    for (int kt = 0; kt < 5; ++kt)
      #pragma unroll
      for (int n = 0; n < 2; ++n){
        short8 wf = *(const short8*)(wlds + ((2*qn+n)*5 + kt)*512 + lane*8);
        acc[n] = __builtin_amdgcn_mfma_f32_16x16x32_bf16(xa[kt], wf, acc[n], 0, 0, 0);
      }
    #pragma unroll
    for (int n = 0; n < 2; ++n)
      #pragma unroll
      for (int j = 0; j < 4; ++j)
        st_dev16(h1T + (pan*16 + 4*hi + j)*512 + (4*m + 2*qn + n)*16 + lo,
                 f2bf(tanh_fast(acc[n][j] + b0v[n])));
  };
  auto phase2 = [&](unsigned short* h1T, unsigned short* h2T){
    short8 ha[16];
    #pragma unroll
    for (int kt = 0; kt < 16; ++kt)
      ha[kt] = ld_dev(h1T + (pan*16 + lo)*512 + kt*32 + (hi<<3));
    VMW0; SCHB;
    f32x4 acc[2]; acc[0] = f32x4{0,0,0,0}; acc[1] = f32x4{0,0,0,0};
    #pragma unroll
    for (int kt = 0; kt < 16; ++kt)
      #pragma unroll
      for (int n = 0; n < 2; ++n){
        short8 wf = *(const short8*)(wlds + (20 + (2*qn+n)*16 + kt)*512 + lane*8);
        acc[n] = __builtin_amdgcn_mfma_f32_16x16x32_bf16(ha[kt], wf, acc[n], 0, 0, 0);
      }
    #pragma unroll
    for (int n = 0; n < 2; ++n)
      #pragma unroll
      for (int j = 0; j < 4; ++j)
        st_dev16(h2T + (pan*16 + 4*hi + j)*512 + (4*m + 2*qn + n)*16 + lo,
                 f2bf(tanh_fast(acc[n][j] + b1v[n])));
  };
  auto phase3 = [&](unsigned short* h2T, unsigned short* gx,
                    float (&yr)[4], float (&yn)[4], int r0, int t, float dt, int stage){
    if (st_own){
      short8 h2a[16];
      #pragma unroll
      for (int kt = 0; kt < 16; ++kt)
        h2a[kt] = ld_dev(h2T + (pan*16 + lo)*512 + kt*32 + (hi<<3));
      VMW0; SCHB;
      f32x4 a3 = f32x4{0,0,0,0};
      #pragma unroll
      for (int kt = 0; kt < 16; ++kt){
        short8 wf = *(const short8*)(wlds + (84 + kt)*512 + lane*8);
        a3 = __builtin_amdgcn_mfma_f32_16x16x32_bf16(h2a[kt], wf, a3, 0, 0, 0);
      }
      #pragma unroll
      for (int j = 0; j < 4; ++j){
        float k = a3[j] + b2v;
        int row = pan*16 + 4*hi + j;
        if (stage == 0){
          yn[j] = yr[j] + dt*(2.0f/9.0f)*k;
          st_dev16(gx + row*XSTR + c3, f2bf(yr[j] + 0.5f*dt*k));
        } else if (stage == 1){
          yn[j] += dt*(1.0f/3.0f)*k;
          st_dev16(gx + row*XSTR + c3, f2bf(yr[j] + 0.75f*dt*k));
        } else {
          yn[j] += dt*(4.0f/9.0f)*k;
          yr[j] = yn[j];
          st_dev16(gx + row*XSTR + c3, f2bf(yr[j]));
          __builtin_nontemporal_store(yr[j], &out[((r0 + row)*T_ + t)*L_ + c3]);
        }
      }
    }
  };

  // Bosh3 main loop, ping-pong interleaved
  for (int t = 1; t < T_; ++t){
    float dt = dtl[t-1];
    for (int s = 0; s < 3; ++s){
      wait(cA, tgtA); phase1(gxA, h1A); sig(cA);
      wait(cB, tgtB); phase1(gxB, h1B); sig(cB);
      wait(cA, tgtA); phase2(h1A, h2A); sig(cA);
      wait(cB, tgtB); phase2(h1B, h2B); sig(cB);
      wait(cA, tgtA); phase3(h2A, gxA, yrA, ynA, r0A, t, dt, s); sig(cA);
      wait(cB, tgtB); phase3(h2B, gxB, yrB, ynB, r0B, t, dt, s); sig(cB);
    }
  }
}

extern "C" void kernel_launch(void* const* d_in, const int* in_sizes, int n_in,
                              void* d_out, int out_size, void* d_ws, size_t ws_size,
                              hipStream_t stream) {
  const float* x0   = (const float*)d_in[0];
  const float* ts   = (const float*)d_in[1];
  const float* args = (const float*)d_in[2];
  const float* W0   = (const float*)d_in[3];
  const float* b0   = (const float*)d_in[4];
  const float* W1   = (const float*)d_in[5];
  const float* b1   = (const float*)d_in[6];
  const float* W2   = (const float*)d_in[7];
  const float* b2   = (const float*)d_in[8];
  unsigned short* wp = (unsigned short*)d_ws;   // ~5.7 MB used
  float* out = (float*)d_out;

  prep_weights<<<(WTOT + 192 + 255)/256, 256, 0, stream>>>(W0, W1, W2, ts, wp);
  ode_main<<<NBLK, 256, 0, stream>>>(x0, args, b0, b1, b2, wp, out);
}